// Round 1
// baseline (1200.594 us; speedup 1.0000x reference)
//
#include <hip/hip_runtime.h>

typedef unsigned short u16;
typedef __bf16 bf16x8 __attribute__((ext_vector_type(8)));
typedef float f32x4 __attribute__((ext_vector_type(4)));

#define B_SZ   4096
#define H_NUM  32
#define F_DIM  1024
#define NTOT   (H_NUM * F_DIM)   // 32768
#define N_CAT  8
#define CAT_D  16
#define N_CONT 24
#define LN_EPS 1e-5f

__device__ __forceinline__ u16 f2bf(float f) {
    unsigned int u = __builtin_bit_cast(unsigned int, f);
    unsigned int r = (u + 0x7FFFu + ((u >> 16) & 1u)) >> 16;
    return (u16)r;
}

__device__ __forceinline__ void gl2lds16(const void* g, void* l) {
    __builtin_amdgcn_global_load_lds(
        (const __attribute__((address_space(1))) void*)g,
        (__attribute__((address_space(3))) void*)l,
        16, 0, 0);
}

__device__ __forceinline__ float wave_sum(float v) {
#pragma unroll
    for (int o = 32; o; o >>= 1) v += __shfl_xor(v, o);
    return v;
}

// ---------------- z f32 -> bf16 ----------------
__global__ __launch_bounds__(256) void zconv(const float* __restrict__ z,
                                             u16* __restrict__ zb) {
    int i = blockIdx.x * 256 + threadIdx.x;      // one float4 per thread
    float4 v = ((const float4*)z)[i];
    ushort4 o;
    o.x = f2bf(v.x); o.y = f2bf(v.y); o.z = f2bf(v.z); o.w = f2bf(v.w);
    ((ushort4*)zb)[i] = o;
}

// ---------------- W_proj [h][f][d] f32 -> Wt [h][d][f] bf16 ----------------
__global__ __launch_bounds__(256) void transpose_w(const float* __restrict__ W,
                                                   u16* __restrict__ Wt) {
    __shared__ u16 tile[64][72];
    const int h = blockIdx.z;
    const int f0 = blockIdx.x * 64;
    const int d0 = blockIdx.y * 64;
    const float* Wh = W + (size_t)h * F_DIM * F_DIM;
    u16* Wth = Wt + (size_t)h * F_DIM * F_DIM;
    const int t = threadIdx.x;

#pragma unroll
    for (int i = 0; i < 4; ++i) {
        int idx = i * 256 + t;        // 0..1023
        int fr = idx >> 4;            // 0..63
        int c4 = idx & 15;            // 0..15
        float4 v = *(const float4*)(Wh + (size_t)(f0 + fr) * F_DIM + d0 + c4 * 4);
        tile[fr][c4 * 4 + 0] = f2bf(v.x);
        tile[fr][c4 * 4 + 1] = f2bf(v.y);
        tile[fr][c4 * 4 + 2] = f2bf(v.z);
        tile[fr][c4 * 4 + 3] = f2bf(v.w);
    }
    __syncthreads();
#pragma unroll
    for (int i = 0; i < 2; ++i) {
        int idx = i * 256 + t;        // 0..511
        int dr = idx >> 3;            // 0..63
        int c8 = idx & 7;             // 0..7
        __attribute__((aligned(16))) u16 tmp[8];
#pragma unroll
        for (int j = 0; j < 8; ++j) tmp[j] = tile[c8 * 8 + j][dr];
        *(uint4*)(Wth + (size_t)(d0 + dr) * F_DIM + f0 + c8 * 8) = *(const uint4*)tmp;
    }
}

// ---------------- GEMM: C[M=4096, N=32768] = A[4096,1024] * Bt[n][k], + b_proj ----------------
__global__ __launch_bounds__(256) void gemm_bt(const u16* __restrict__ A,
                                               const u16* __restrict__ Bt,
                                               const float* __restrict__ bproj,
                                               float* __restrict__ C) {
    __shared__ u16 sA[128 * 64];
    __shared__ u16 sB[128 * 64];
    const int t = threadIdx.x;
    const int wid = t >> 6;
    const int lane = t & 63;
    const int l16 = lane & 15;
    const int lk = lane >> 4;
    const int wr = wid >> 1;
    const int wc = wid & 1;
    const int m0 = blockIdx.y * 128;
    const int n0 = blockIdx.x * 128;

    f32x4 acc[4][4];
    const f32x4 zero = {0.f, 0.f, 0.f, 0.f};
#pragma unroll
    for (int m = 0; m < 4; ++m)
#pragma unroll
        for (int n = 0; n < 4; ++n) acc[m][n] = zero;

    for (int k0 = 0; k0 < 1024; k0 += 64) {
#pragma unroll
        for (int q = 0; q < 4; ++q) {
            int ci = q * 256 + t;
            int r = ci >> 3, c8 = ci & 7;
            gl2lds16(A + ((size_t)(m0 + r) << 10) + k0 + c8 * 8,
                     sA + (size_t)(q * 256 + (wid << 6)) * 8);
        }
#pragma unroll
        for (int q = 0; q < 4; ++q) {
            int ci = q * 256 + t;
            int r = ci >> 3, c8 = ci & 7;
            gl2lds16(Bt + ((size_t)(n0 + r) << 10) + k0 + c8 * 8,
                     sB + (size_t)(q * 256 + (wid << 6)) * 8);
        }
        __syncthreads();
#pragma unroll
        for (int kk = 0; kk < 64; kk += 32) {
            bf16x8 a[4], bf[4];
#pragma unroll
            for (int m = 0; m < 4; ++m)
                a[m] = *(const bf16x8*)(sA + (wr * 64 + m * 16 + l16) * 64 + kk + lk * 8);
#pragma unroll
            for (int n = 0; n < 4; ++n)
                bf[n] = *(const bf16x8*)(sB + (wc * 64 + n * 16 + l16) * 64 + kk + lk * 8);
#pragma unroll
            for (int m = 0; m < 4; ++m)
#pragma unroll
                for (int n = 0; n < 4; ++n)
                    acc[m][n] = __builtin_amdgcn_mfma_f32_16x16x32_bf16(a[m], bf[n], acc[m][n], 0, 0, 0);
        }
        __syncthreads();
    }

#pragma unroll
    for (int n = 0; n < 4; ++n) {
        int col = n0 + wc * 64 + n * 16 + l16;
        float bias = bproj[col];
#pragma unroll
        for (int m = 0; m < 4; ++m) {
            int rbase = m0 + wr * 64 + m * 16 + lk * 4;
#pragma unroll
            for (int j = 0; j < 4; ++j)
                C[(size_t)(rbase + j) * NTOT + col] = acc[m][n][j] + bias;
        }
    }
}

// ---------------- LN stats: mean & rstd per batch row ----------------
__global__ __launch_bounds__(256) void ln_stats(const float* __restrict__ C,
                                                float* __restrict__ murs) {
    const int b = blockIdx.x;
    const float4* p = (const float4*)(C + (size_t)b * NTOT);
    float s = 0.f, s2 = 0.f;
    for (int i = threadIdx.x; i < NTOT / 4; i += 256) {
        float4 v = p[i];
        s += v.x + v.y + v.z + v.w;
        s2 += v.x * v.x + v.y * v.y + v.z * v.z + v.w * v.w;
    }
    s = wave_sum(s);
    s2 = wave_sum(s2);
    __shared__ float red[8];
    int wid = threadIdx.x >> 6, lane = threadIdx.x & 63;
    if (lane == 0) { red[wid] = s; red[4 + wid] = s2; }
    __syncthreads();
    if (threadIdx.x == 0) {
        float S = red[0] + red[1] + red[2] + red[3];
        float S2 = red[4] + red[5] + red[6] + red[7];
        float m = S / (float)NTOT;
        float var = S2 / (float)NTOT - m * m;
        murs[b] = m;
        murs[B_SZ + b] = rsqrtf(var + LN_EPS);
    }
}

// ---------------- normalize + relu (in place) + heads ----------------
__global__ __launch_bounds__(256) void heads(float* __restrict__ lat_base,
                                             const float* __restrict__ murs,
                                             const float* __restrict__ lnw,
                                             const float* __restrict__ lnb,
                                             const float* __restrict__ Wcat,
                                             const float* __restrict__ bcat,
                                             const float* __restrict__ Wcont,
                                             const float* __restrict__ bcont,
                                             float* __restrict__ pcat,
                                             float* __restrict__ pcont) {
    const int b = blockIdx.x;
    const int t = threadIdx.x;
    const int wid = t >> 6, lane = t & 63;
    const float mu = murs[b];
    const float rs = murs[B_SZ + b];
    float* lat = lat_base + (size_t)b * NTOT;
    __shared__ float red[4][16];

    for (int h = 0; h < H_NUM; ++h) {
        const int f = t * 4;
        const size_t off = (size_t)h * F_DIM + f;
        float4 x = *(float4*)(lat + off);
        float4 w = *(const float4*)(lnw + off);
        float4 bb = *(const float4*)(lnb + off);
        float y0 = fmaxf(0.f, (x.x - mu) * rs * w.x + bb.x);
        float y1 = fmaxf(0.f, (x.y - mu) * rs * w.y + bb.y);
        float y2 = fmaxf(0.f, (x.z - mu) * rs * w.z + bb.z);
        float y3 = fmaxf(0.f, (x.w - mu) * rs * w.w + bb.w);
        float4 yo; yo.x = y0; yo.y = y1; yo.z = y2; yo.w = y3;
        *(float4*)(lat + off) = yo;

        if (h < N_CAT) {
            float la[16];
#pragma unroll
            for (int c = 0; c < 16; ++c) la[c] = 0.f;
            const float* Wc = Wcat + (size_t)h * F_DIM * CAT_D;
            float ys[4] = {y0, y1, y2, y3};
#pragma unroll
            for (int i = 0; i < 4; ++i) {
                const float4* wrow = (const float4*)(Wc + (size_t)(f + i) * CAT_D);
                float yi = ys[i];
#pragma unroll
                for (int q = 0; q < 4; ++q) {
                    float4 wv = wrow[q];
                    la[q * 4 + 0] += yi * wv.x;
                    la[q * 4 + 1] += yi * wv.y;
                    la[q * 4 + 2] += yi * wv.z;
                    la[q * 4 + 3] += yi * wv.w;
                }
            }
#pragma unroll
            for (int o = 32; o; o >>= 1)
#pragma unroll
                for (int c = 0; c < 16; ++c) la[c] += __shfl_xor(la[c], o);
            if (lane == 0) {
#pragma unroll
                for (int c = 0; c < 16; ++c) red[wid][c] = la[c];
            }
            __syncthreads();
            if (t < 16) {
                float lg = red[0][t] + red[1][t] + red[2][t] + red[3][t] + bcat[h * CAT_D + t];
                float mx = lg;
#pragma unroll
                for (int o = 8; o; o >>= 1) mx = fmaxf(mx, __shfl_xor(mx, o, 16));
                float e = __expf(lg - mx);
                float sm = e;
#pragma unroll
                for (int o = 8; o; o >>= 1) sm += __shfl_xor(sm, o, 16);
                pcat[(size_t)b * (N_CAT * CAT_D) + h * CAT_D + t] = e / sm;
            }
            __syncthreads();
        } else {
            const float* Wn = Wcont + (size_t)(h - N_CAT) * F_DIM;
            float4 wv = *(const float4*)(Wn + f);
            float part = y0 * wv.x + y1 * wv.y + y2 * wv.z + y3 * wv.w;
            part = wave_sum(part);
            if (lane == 0) red[wid][0] = part;
            __syncthreads();
            if (t == 0)
                pcont[(size_t)b * N_CONT + (h - N_CAT)] =
                    red[0][0] + red[1][0] + red[2][0] + red[3][0] + bcont[h - N_CAT];
            __syncthreads();
        }
    }
}

extern "C" void kernel_launch(void* const* d_in, const int* in_sizes, int n_in,
                              void* d_out, int out_size, void* d_ws, size_t ws_size,
                              hipStream_t stream) {
    const float* z     = (const float*)d_in[0];
    // d_in[1] = edge (unused by reference computation)
    const float* Wp    = (const float*)d_in[2];
    const float* bp    = (const float*)d_in[3];
    const float* lnw   = (const float*)d_in[4];
    const float* lnb   = (const float*)d_in[5];
    const float* Wcat  = (const float*)d_in[6];
    const float* bcat  = (const float*)d_in[7];
    const float* Wcont = (const float*)d_in[8];
    const float* bcont = (const float*)d_in[9];

    float* out    = (float*)d_out;
    float* pcat   = out;                                   // [4096, 8, 16]
    float* pcont  = out + (size_t)B_SZ * N_CAT * CAT_D;    // [4096, 24, 1]
    float* latent = pcont + (size_t)B_SZ * N_CONT;         // [4096, 32, 1024]

    u16* zb   = (u16*)d_ws;                                // 4096*1024 bf16
    u16* Wt   = zb + (size_t)B_SZ * F_DIM;                 // 32768*1024 bf16
    float* murs = (float*)(Wt + (size_t)NTOT * F_DIM);     // 2*4096 f32

    zconv<<<dim3(B_SZ * F_DIM / 1024), 256, 0, stream>>>(z, zb);
    transpose_w<<<dim3(16, 16, 32), 256, 0, stream>>>(Wp, Wt);
    gemm_bt<<<dim3(NTOT / 128, B_SZ / 128), 256, 0, stream>>>(zb, Wt, bp, latent);
    ln_stats<<<dim3(B_SZ), 256, 0, stream>>>(latent, murs);
    heads<<<dim3(B_SZ), 256, 0, stream>>>(latent, murs, lnw, lnb, Wcat, bcat,
                                          Wcont, bcont, pcat, pcont);
}

// Round 2
// 1128.310 us; speedup vs baseline: 1.0641x; 1.0641x over previous
//
#include <hip/hip_runtime.h>

typedef unsigned short u16;
typedef __bf16 bf16x8 __attribute__((ext_vector_type(8)));
typedef float f32x4 __attribute__((ext_vector_type(4)));

#define B_SZ   4096
#define H_NUM  32
#define F_DIM  1024
#define NTOT   (H_NUM * F_DIM)   // 32768
#define N_CAT  8
#define CAT_D  16
#define N_CONT 24
#define LN_EPS 1e-5f

__device__ __forceinline__ u16 f2bf(float f) {
    unsigned int u = __builtin_bit_cast(unsigned int, f);
    unsigned int r = (u + 0x7FFFu + ((u >> 16) & 1u)) >> 16;
    return (u16)r;
}

__device__ __forceinline__ void gl2lds16(const void* g, void* l) {
    __builtin_amdgcn_global_load_lds(
        (const __attribute__((address_space(1))) void*)g,
        (__attribute__((address_space(3))) void*)l,
        16, 0, 0);
}

__device__ __forceinline__ float wave_sum(float v) {
#pragma unroll
    for (int o = 32; o; o >>= 1) v += __shfl_xor(v, o);
    return v;
}

// ---------------- z f32 -> bf16 ----------------
__global__ __launch_bounds__(256) void zconv(const float* __restrict__ z,
                                             u16* __restrict__ zb) {
    int i = blockIdx.x * 256 + threadIdx.x;      // one float4 per thread
    float4 v = ((const float4*)z)[i];
    ushort4 o;
    o.x = f2bf(v.x); o.y = f2bf(v.y); o.z = f2bf(v.z); o.w = f2bf(v.w);
    ((ushort4*)zb)[i] = o;
}

// ---------------- W_proj [h][f][d] f32 -> Wt [h][d][f] bf16 ----------------
__global__ __launch_bounds__(256) void transpose_w(const float* __restrict__ W,
                                                   u16* __restrict__ Wt) {
    __shared__ u16 tile[64][72];
    const int h = blockIdx.z;
    const int f0 = blockIdx.x * 64;
    const int d0 = blockIdx.y * 64;
    const float* Wh = W + (size_t)h * F_DIM * F_DIM;
    u16* Wth = Wt + (size_t)h * F_DIM * F_DIM;
    const int t = threadIdx.x;

#pragma unroll
    for (int i = 0; i < 4; ++i) {
        int idx = i * 256 + t;        // 0..1023
        int fr = idx >> 4;            // 0..63
        int c4 = idx & 15;            // 0..15
        float4 v = *(const float4*)(Wh + (size_t)(f0 + fr) * F_DIM + d0 + c4 * 4);
        tile[fr][c4 * 4 + 0] = f2bf(v.x);
        tile[fr][c4 * 4 + 1] = f2bf(v.y);
        tile[fr][c4 * 4 + 2] = f2bf(v.z);
        tile[fr][c4 * 4 + 3] = f2bf(v.w);
    }
    __syncthreads();
#pragma unroll
    for (int i = 0; i < 2; ++i) {
        int idx = i * 256 + t;        // 0..511
        int dr = idx >> 3;            // 0..63
        int c8 = idx & 7;             // 0..7
        __attribute__((aligned(16))) u16 tmp[8];
#pragma unroll
        for (int j = 0; j < 8; ++j) tmp[j] = tile[c8 * 8 + j][dr];
        *(uint4*)(Wth + (size_t)(d0 + dr) * F_DIM + f0 + c8 * 8) = *(const uint4*)tmp;
    }
}

// ---------------- GEMM: C[M=4096, N=32768] = A[4096,1024] * Bt[n][k], + b_proj ----------------
__global__ __launch_bounds__(256) void gemm_bt(const u16* __restrict__ A,
                                               const u16* __restrict__ Bt,
                                               const float* __restrict__ bproj,
                                               float* __restrict__ C) {
    __shared__ u16 sA[128 * 64];
    __shared__ u16 sB[128 * 64];
    const int t = threadIdx.x;
    const int wid = t >> 6;
    const int lane = t & 63;
    const int l16 = lane & 15;
    const int lk = lane >> 4;
    const int wr = wid >> 1;
    const int wc = wid & 1;

    // XCD-aware bijective swizzle (nwg = 8192, 8192 % 8 == 0)
    const int nwg = (NTOT / 128) * (B_SZ / 128);     // 8192
    const int q = nwg >> 3;
    const int wg = blockIdx.x;
    const int sw = (wg & 7) * q + (wg >> 3);
    const int nx = NTOT / 128;                       // 256
    const int m0 = (sw / nx) * 128;
    const int n0 = (sw % nx) * 128;

    f32x4 acc[4][4];
    const f32x4 zero = {0.f, 0.f, 0.f, 0.f};
#pragma unroll
    for (int m = 0; m < 4; ++m)
#pragma unroll
        for (int n = 0; n < 4; ++n) acc[m][n] = zero;

    for (int k0 = 0; k0 < 1024; k0 += 64) {
#pragma unroll
        for (int q2 = 0; q2 < 4; ++q2) {
            int ci = q2 * 256 + t;
            int r = ci >> 3, c8 = ci & 7;
            gl2lds16(A + ((size_t)(m0 + r) << 10) + k0 + c8 * 8,
                     sA + (size_t)(q2 * 256 + (wid << 6)) * 8);
        }
#pragma unroll
        for (int q2 = 0; q2 < 4; ++q2) {
            int ci = q2 * 256 + t;
            int r = ci >> 3, c8 = ci & 7;
            gl2lds16(Bt + ((size_t)(n0 + r) << 10) + k0 + c8 * 8,
                     sB + (size_t)(q2 * 256 + (wid << 6)) * 8);
        }
        __syncthreads();
#pragma unroll
        for (int kk = 0; kk < 64; kk += 32) {
            bf16x8 a[4], bf[4];
#pragma unroll
            for (int m = 0; m < 4; ++m)
                a[m] = *(const bf16x8*)(sA + (wr * 64 + m * 16 + l16) * 64 + kk + lk * 8);
#pragma unroll
            for (int n = 0; n < 4; ++n)
                bf[n] = *(const bf16x8*)(sB + (wc * 64 + n * 16 + l16) * 64 + kk + lk * 8);
#pragma unroll
            for (int m = 0; m < 4; ++m)
#pragma unroll
                for (int n = 0; n < 4; ++n)
                    acc[m][n] = __builtin_amdgcn_mfma_f32_16x16x32_bf16(a[m], bf[n], acc[m][n], 0, 0, 0);
        }
        __syncthreads();
    }

#pragma unroll
    for (int n = 0; n < 4; ++n) {
        int col = n0 + wc * 64 + n * 16 + l16;
        float bias = bproj[col];
#pragma unroll
        for (int m = 0; m < 4; ++m) {
            int rbase = m0 + wr * 64 + m * 16 + lk * 4;
#pragma unroll
            for (int j = 0; j < 4; ++j)
                C[(size_t)(rbase + j) * NTOT + col] = acc[m][n][j] + bias;
        }
    }
}

// ---------------- LN stats: mean & rstd per batch row ----------------
__global__ __launch_bounds__(256) void ln_stats(const float* __restrict__ C,
                                                float* __restrict__ murs) {
    const int b = blockIdx.x;
    const float4* p = (const float4*)(C + (size_t)b * NTOT);
    float s = 0.f, s2 = 0.f;
    for (int i = threadIdx.x; i < NTOT / 4; i += 256) {
        float4 v = p[i];
        s += v.x + v.y + v.z + v.w;
        s2 += v.x * v.x + v.y * v.y + v.z * v.z + v.w * v.w;
    }
    s = wave_sum(s);
    s2 = wave_sum(s2);
    __shared__ float red[8];
    int wid = threadIdx.x >> 6, lane = threadIdx.x & 63;
    if (lane == 0) { red[wid] = s; red[4 + wid] = s2; }
    __syncthreads();
    if (threadIdx.x == 0) {
        float S = red[0] + red[1] + red[2] + red[3];
        float S2 = red[4] + red[5] + red[6] + red[7];
        float m = S / (float)NTOT;
        float var = S2 / (float)NTOT - m * m;
        murs[b] = m;
        murs[B_SZ + b] = rsqrtf(var + LN_EPS);
    }
}

// ---------------- normalize + relu (in place) + heads, one block per (h, b) ----------------
__global__ __launch_bounds__(256) void heads2(float* __restrict__ lat_base,
                                              const float* __restrict__ murs,
                                              const float* __restrict__ lnw,
                                              const float* __restrict__ lnb,
                                              const float* __restrict__ Wcat,
                                              const float* __restrict__ bcat,
                                              const float* __restrict__ Wcont,
                                              const float* __restrict__ bcont,
                                              float* __restrict__ pcat,
                                              float* __restrict__ pcont) {
    const int h = blockIdx.x;          // fastest: 32 consecutive blocks stream one b's 128KB
    const int b = blockIdx.y;
    const int t = threadIdx.x;
    const int wid = t >> 6, lane = t & 63;
    const float mu = murs[b];
    const float rs = murs[B_SZ + b];
    float* lat = lat_base + (size_t)b * NTOT + (size_t)h * F_DIM;

    __shared__ float y[F_DIM];
    __shared__ float red[4][16];

    float4 x = *(const float4*)(lat + t * 4);
    float4 w = *(const float4*)(lnw + (size_t)h * F_DIM + t * 4);
    float4 bb = *(const float4*)(lnb + (size_t)h * F_DIM + t * 4);
    float4 yo;
    yo.x = fmaxf(0.f, (x.x - mu) * rs * w.x + bb.x);
    yo.y = fmaxf(0.f, (x.y - mu) * rs * w.y + bb.y);
    yo.z = fmaxf(0.f, (x.z - mu) * rs * w.z + bb.z);
    yo.w = fmaxf(0.f, (x.w - mu) * rs * w.w + bb.w);
    *(float4*)(lat + t * 4) = yo;
    *(float4*)(y + t * 4) = yo;
    __syncthreads();

    if (h < N_CAT) {
        // col-per-lane GEMV: c = t&15 (coalesced W_cat lines, fully utilized)
        const int c = t & 15;
        const int fg = t >> 4;                    // 0..15
        const float* Wc = Wcat + (size_t)h * F_DIM * CAT_D;
        float acc = 0.f;
#pragma unroll 8
        for (int i = 0; i < 64; ++i) {
            int f = i * 16 + fg;
            acc += y[f] * Wc[f * CAT_D + c];
        }
        // reduce fg&3 within wave (lane = (fg&3)*16 + c)
        acc += __shfl_xor(acc, 16);
        acc += __shfl_xor(acc, 32);
        if (lane < 16) red[wid][lane] = acc;      // lane == c here
        __syncthreads();
        if (t < 16) {
            float lg = red[0][t] + red[1][t] + red[2][t] + red[3][t] + bcat[h * CAT_D + t];
            float mx = lg;
#pragma unroll
            for (int o = 8; o; o >>= 1) mx = fmaxf(mx, __shfl_xor(mx, o, 16));
            float e = __expf(lg - mx);
            float sm = e;
#pragma unroll
            for (int o = 8; o; o >>= 1) sm += __shfl_xor(sm, o, 16);
            pcat[(size_t)b * (N_CAT * CAT_D) + h * CAT_D + t] = e / sm;
        }
    } else {
        const float* Wn = Wcont + (size_t)(h - N_CAT) * F_DIM;
        float4 wv = *(const float4*)(Wn + t * 4);
        float part = yo.x * wv.x + yo.y * wv.y + yo.z * wv.z + yo.w * wv.w;
        part = wave_sum(part);
        if (lane == 0) red[wid][0] = part;
        __syncthreads();
        if (t == 0)
            pcont[(size_t)b * N_CONT + (h - N_CAT)] =
                red[0][0] + red[1][0] + red[2][0] + red[3][0] + bcont[h - N_CAT];
    }
}

extern "C" void kernel_launch(void* const* d_in, const int* in_sizes, int n_in,
                              void* d_out, int out_size, void* d_ws, size_t ws_size,
                              hipStream_t stream) {
    const float* z     = (const float*)d_in[0];
    // d_in[1] = edge (unused by reference computation)
    const float* Wp    = (const float*)d_in[2];
    const float* bp    = (const float*)d_in[3];
    const float* lnw   = (const float*)d_in[4];
    const float* lnb   = (const float*)d_in[5];
    const float* Wcat  = (const float*)d_in[6];
    const float* bcat  = (const float*)d_in[7];
    const float* Wcont = (const float*)d_in[8];
    const float* bcont = (const float*)d_in[9];

    float* out    = (float*)d_out;
    float* pcat   = out;                                   // [4096, 8, 16]
    float* pcont  = out + (size_t)B_SZ * N_CAT * CAT_D;    // [4096, 24, 1]
    float* latent = pcont + (size_t)B_SZ * N_CONT;         // [4096, 32, 1024]

    u16* zb   = (u16*)d_ws;                                // 4096*1024 bf16
    u16* Wt   = zb + (size_t)B_SZ * F_DIM;                 // 32768*1024 bf16
    float* murs = (float*)(Wt + (size_t)NTOT * F_DIM);     // 2*4096 f32

    zconv<<<dim3(B_SZ * F_DIM / 1024), 256, 0, stream>>>(z, zb);
    transpose_w<<<dim3(16, 16, 32), 256, 0, stream>>>(Wp, Wt);
    gemm_bt<<<dim3((NTOT / 128) * (B_SZ / 128)), 256, 0, stream>>>(zb, Wt, bp, latent);
    ln_stats<<<dim3(B_SZ), 256, 0, stream>>>(latent, murs);
    heads2<<<dim3(H_NUM, B_SZ), 256, 0, stream>>>(latent, murs, lnw, lnb, Wcat, bcat,
                                                  Wcont, bcont, pcat, pcont);
}

// Round 3
// 1032.821 us; speedup vs baseline: 1.1624x; 1.0925x over previous
//
#include <hip/hip_runtime.h>

typedef unsigned short u16;
typedef __bf16 bf16x8 __attribute__((ext_vector_type(8)));
typedef float f32x4 __attribute__((ext_vector_type(4)));

#define B_SZ   4096
#define H_NUM  32
#define F_DIM  1024
#define NTOT   (H_NUM * F_DIM)   // 32768
#define N_CAT  8
#define CAT_D  16
#define N_CONT 24
#define LN_EPS 1e-5f
#define NSTRIP (NTOT / 128)      // 256 n-strips in the GEMM

__device__ __forceinline__ u16 f2bf(float f) {
    unsigned int u = __builtin_bit_cast(unsigned int, f);
    unsigned int r = (u + 0x7FFFu + ((u >> 16) & 1u)) >> 16;
    return (u16)r;
}

__device__ __forceinline__ void gl2lds16(const void* g, void* l) {
    __builtin_amdgcn_global_load_lds(
        (const __attribute__((address_space(1))) void*)g,
        (__attribute__((address_space(3))) void*)l,
        16, 0, 0);
}

__device__ __forceinline__ float wave_sum(float v) {
#pragma unroll
    for (int o = 32; o; o >>= 1) v += __shfl_xor(v, o);
    return v;
}

// ---------------- z f32 -> bf16 ----------------
__global__ __launch_bounds__(256) void zconv(const float* __restrict__ z,
                                             u16* __restrict__ zb) {
    int i = blockIdx.x * 256 + threadIdx.x;      // one float4 per thread
    float4 v = ((const float4*)z)[i];
    ushort4 o;
    o.x = f2bf(v.x); o.y = f2bf(v.y); o.z = f2bf(v.z); o.w = f2bf(v.w);
    ((ushort4*)zb)[i] = o;
}

// ---------------- W_proj [h][f][d] f32 -> Wt [h][d][f] bf16 ----------------
__global__ __launch_bounds__(256) void transpose_w(const float* __restrict__ W,
                                                   u16* __restrict__ Wt) {
    __shared__ u16 tile[64][72];
    const int h = blockIdx.z;
    const int f0 = blockIdx.x * 64;
    const int d0 = blockIdx.y * 64;
    const float* Wh = W + (size_t)h * F_DIM * F_DIM;
    u16* Wth = Wt + (size_t)h * F_DIM * F_DIM;
    const int t = threadIdx.x;

#pragma unroll
    for (int i = 0; i < 4; ++i) {
        int idx = i * 256 + t;        // 0..1023
        int fr = idx >> 4;            // 0..63
        int c4 = idx & 15;            // 0..15
        float4 v = *(const float4*)(Wh + (size_t)(f0 + fr) * F_DIM + d0 + c4 * 4);
        tile[fr][c4 * 4 + 0] = f2bf(v.x);
        tile[fr][c4 * 4 + 1] = f2bf(v.y);
        tile[fr][c4 * 4 + 2] = f2bf(v.z);
        tile[fr][c4 * 4 + 3] = f2bf(v.w);
    }
    __syncthreads();
#pragma unroll
    for (int i = 0; i < 2; ++i) {
        int idx = i * 256 + t;        // 0..511
        int dr = idx >> 3;            // 0..63
        int c8 = idx & 7;             // 0..7
        __attribute__((aligned(16))) u16 tmp[8];
#pragma unroll
        for (int j = 0; j < 8; ++j) tmp[j] = tile[c8 * 8 + j][dr];
        *(uint4*)(Wth + (size_t)(d0 + dr) * F_DIM + f0 + c8 * 8) = *(const uint4*)tmp;
    }
}

// ---------------- GEMM + per-block LN partial sums ----------------
__global__ __launch_bounds__(256) void gemm_bt(const u16* __restrict__ A,
                                               const u16* __restrict__ Bt,
                                               const float* __restrict__ bproj,
                                               float* __restrict__ C,
                                               float* __restrict__ psum,
                                               float* __restrict__ psumsq) {
    __shared__ u16 sA[128 * 64];
    __shared__ u16 sB[128 * 64];
    __shared__ float sred[2][128];
    __shared__ float s2red[2][128];
    const int t = threadIdx.x;
    const int wid = t >> 6;
    const int lane = t & 63;
    const int l16 = lane & 15;
    const int lk = lane >> 4;
    const int wr = wid >> 1;
    const int wc = wid & 1;

    // XCD-aware bijective swizzle (nwg = 8192, 8192 % 8 == 0)
    const int nwg = NSTRIP * (B_SZ / 128);           // 8192
    const int q = nwg >> 3;
    const int wg = blockIdx.x;
    const int sw = (wg & 7) * q + (wg >> 3);
    const int m0 = (sw / NSTRIP) * 128;
    const int n0 = (sw % NSTRIP) * 128;

    f32x4 acc[4][4];
    const f32x4 zero = {0.f, 0.f, 0.f, 0.f};
#pragma unroll
    for (int m = 0; m < 4; ++m)
#pragma unroll
        for (int n = 0; n < 4; ++n) acc[m][n] = zero;

    for (int k0 = 0; k0 < 1024; k0 += 64) {
#pragma unroll
        for (int q2 = 0; q2 < 4; ++q2) {
            int ci = q2 * 256 + t;
            int r = ci >> 3, c8 = ci & 7;
            gl2lds16(A + ((size_t)(m0 + r) << 10) + k0 + c8 * 8,
                     sA + (size_t)(q2 * 256 + (wid << 6)) * 8);
        }
#pragma unroll
        for (int q2 = 0; q2 < 4; ++q2) {
            int ci = q2 * 256 + t;
            int r = ci >> 3, c8 = ci & 7;
            gl2lds16(Bt + ((size_t)(n0 + r) << 10) + k0 + c8 * 8,
                     sB + (size_t)(q2 * 256 + (wid << 6)) * 8);
        }
        __syncthreads();
#pragma unroll
        for (int kk = 0; kk < 64; kk += 32) {
            bf16x8 a[4], bf[4];
#pragma unroll
            for (int m = 0; m < 4; ++m)
                a[m] = *(const bf16x8*)(sA + (wr * 64 + m * 16 + l16) * 64 + kk + lk * 8);
#pragma unroll
            for (int n = 0; n < 4; ++n)
                bf[n] = *(const bf16x8*)(sB + (wc * 64 + n * 16 + l16) * 64 + kk + lk * 8);
#pragma unroll
            for (int m = 0; m < 4; ++m)
#pragma unroll
                for (int n = 0; n < 4; ++n)
                    acc[m][n] = __builtin_amdgcn_mfma_f32_16x16x32_bf16(a[m], bf[n], acc[m][n], 0, 0, 0);
        }
        __syncthreads();
    }

    // epilogue: C-write + per-row (sum, sumsq) over this block's 128 cols
    float sm[4][4], s2m[4][4];
#pragma unroll
    for (int m = 0; m < 4; ++m)
#pragma unroll
        for (int j = 0; j < 4; ++j) { sm[m][j] = 0.f; s2m[m][j] = 0.f; }

#pragma unroll
    for (int n = 0; n < 4; ++n) {
        int col = n0 + wc * 64 + n * 16 + l16;
        float bias = bproj[col];
#pragma unroll
        for (int m = 0; m < 4; ++m) {
            int rbase = m0 + wr * 64 + m * 16 + lk * 4;
#pragma unroll
            for (int j = 0; j < 4; ++j) {
                float v = acc[m][n][j] + bias;
                C[(size_t)(rbase + j) * NTOT + col] = v;
                sm[m][j] += v;
                s2m[m][j] += v * v;
            }
        }
    }
    // reduce over the 16 l16 lanes (same rows, different cols)
#pragma unroll
    for (int o = 1; o < 16; o <<= 1) {
#pragma unroll
        for (int m = 0; m < 4; ++m)
#pragma unroll
            for (int j = 0; j < 4; ++j) {
                sm[m][j] += __shfl_xor(sm[m][j], o);
                s2m[m][j] += __shfl_xor(s2m[m][j], o);
            }
    }
    if (l16 == 0) {
#pragma unroll
        for (int m = 0; m < 4; ++m)
#pragma unroll
            for (int j = 0; j < 4; ++j) {
                int r = wr * 64 + m * 16 + lk * 4 + j;
                sred[wc][r] = sm[m][j];
                s2red[wc][r] = s2m[m][j];
            }
    }
    __syncthreads();
    if (t < 128) {
        int strip = n0 >> 7;
        psum[(size_t)(m0 + t) * NSTRIP + strip] = sred[0][t] + sred[1][t];
        psumsq[(size_t)(m0 + t) * NSTRIP + strip] = s2red[0][t] + s2red[1][t];
    }
}

// ---------------- finalize LN stats from partials ----------------
__global__ __launch_bounds__(256) void ln_finalize(const float* __restrict__ psum,
                                                   const float* __restrict__ psumsq,
                                                   float* __restrict__ murs) {
    const int b = blockIdx.x;
    const int t = threadIdx.x;
    float s = psum[(size_t)b * NSTRIP + t];
    float s2 = psumsq[(size_t)b * NSTRIP + t];
    s = wave_sum(s);
    s2 = wave_sum(s2);
    __shared__ float red[8];
    int wid = t >> 6, lane = t & 63;
    if (lane == 0) { red[wid] = s; red[4 + wid] = s2; }
    __syncthreads();
    if (t == 0) {
        float S = red[0] + red[1] + red[2] + red[3];
        float S2 = red[4] + red[5] + red[6] + red[7];
        float m = S / (float)NTOT;
        float var = S2 / (float)NTOT - m * m;
        murs[b] = m;
        murs[B_SZ + b] = rsqrtf(var + LN_EPS);
    }
}

// ---------------- normalize + relu + all heads, one 1024-thread block per b ----------------
// thread t owns float4 indices i = t + k*1024, k=0..7  (h = (t>>8) + 4k, f4 = t&255)
__global__ __launch_bounds__(1024) void headsF(float* __restrict__ lat_base,
                                               const float* __restrict__ murs,
                                               const float* __restrict__ lnw,
                                               const float* __restrict__ lnb,
                                               const float* __restrict__ Wcat,
                                               const float* __restrict__ bcat,
                                               const float* __restrict__ Wcont,
                                               const float* __restrict__ bcont,
                                               float* __restrict__ pcat,
                                               float* __restrict__ pcont) {
    const int b = blockIdx.x;
    const int t = threadIdx.x;
    const int lane = t & 63;
    const int w4 = (t >> 6) & 3;     // wave index within the hb group
    const int hb = t >> 8;           // 0..3
    const int f4 = t & 255;          // float4 index within a head row
    const float mu = murs[b];
    const float rs = murs[B_SZ + b];
    float* lat = lat_base + (size_t)b * NTOT;

    __shared__ float cred[2][4][4][16];   // [k][hb][w4][c]
    __shared__ float nred[6][4][4];       // [k-2][hb][w4]

    float4 y4[8];
#pragma unroll
    for (int k = 0; k < 8; ++k) {
        int i = t + k * 1024;
        float4 x = ((const float4*)lat)[i];
        float4 w = ((const float4*)lnw)[i];
        float4 bv = ((const float4*)lnb)[i];
        float4 yo;
        yo.x = fmaxf(0.f, (x.x - mu) * rs * w.x + bv.x);
        yo.y = fmaxf(0.f, (x.y - mu) * rs * w.y + bv.y);
        yo.z = fmaxf(0.f, (x.z - mu) * rs * w.z + bv.z);
        yo.w = fmaxf(0.f, (x.w - mu) * rs * w.w + bv.w);
        y4[k] = yo;
        ((float4*)lat)[i] = yo;
    }

    // ---- categorical heads: k=0 -> h=hb, k=1 -> h=hb+4 ----
    float cl[2][16];
#pragma unroll
    for (int k = 0; k < 2; ++k) {
        const int h = hb + 4 * k;
        const float4* Wc4 = (const float4*)(Wcat + (size_t)h * F_DIM * CAT_D);
        float yv[4] = {y4[k].x, y4[k].y, y4[k].z, y4[k].w};
#pragma unroll
        for (int c = 0; c < 16; ++c) cl[k][c] = 0.f;
#pragma unroll
        for (int r = 0; r < 4; ++r) {
            float yr = yv[r];
#pragma unroll
            for (int q = 0; q < 4; ++q) {
                float4 wv = Wc4[(f4 * 4 + r) * 4 + q];
                cl[k][q * 4 + 0] += yr * wv.x;
                cl[k][q * 4 + 1] += yr * wv.y;
                cl[k][q * 4 + 2] += yr * wv.z;
                cl[k][q * 4 + 3] += yr * wv.w;
            }
        }
#pragma unroll
        for (int o = 32; o; o >>= 1)
#pragma unroll
            for (int c = 0; c < 16; ++c) cl[k][c] += __shfl_xor(cl[k][c], o);
        if (lane == 0) {
#pragma unroll
            for (int c = 0; c < 16; ++c) cred[k][hb][w4][c] = cl[k][c];
        }
    }

    // ---- continuous heads: k=2..7 -> h = hb + 4k (8..31) ----
    float cp[6];
#pragma unroll
    for (int k = 2; k < 8; ++k) {
        const int h = hb + 4 * k;
        float4 wv = ((const float4*)(Wcont + (size_t)(h - N_CAT) * F_DIM))[f4];
        cp[k - 2] = y4[k].x * wv.x + y4[k].y * wv.y + y4[k].z * wv.z + y4[k].w * wv.w;
    }
#pragma unroll
    for (int o = 32; o; o >>= 1)
#pragma unroll
        for (int k = 0; k < 6; ++k) cp[k] += __shfl_xor(cp[k], o);
    if (lane == 0) {
#pragma unroll
        for (int k = 0; k < 6; ++k) nred[k][hb][w4] = cp[k];
    }
    __syncthreads();

    if (t < 128) {
        // cat finalize + softmax: h = t>>4, c = t&15
        const int h = t >> 4, c = t & 15;
        const int k = h >> 2, hb2 = h & 3;
        float lg = cred[k][hb2][0][c] + cred[k][hb2][1][c] +
                   cred[k][hb2][2][c] + cred[k][hb2][3][c] + bcat[h * CAT_D + c];
        float mx = lg;
#pragma unroll
        for (int o = 8; o; o >>= 1) mx = fmaxf(mx, __shfl_xor(mx, o, 16));
        float e = __expf(lg - mx);
        float sm2 = e;
#pragma unroll
        for (int o = 8; o; o >>= 1) sm2 += __shfl_xor(sm2, o, 16);
        pcat[(size_t)b * (N_CAT * CAT_D) + h * CAT_D + c] = e / sm2;
    } else if (t >= 256 && t < 256 + N_CONT) {
        const int ci = t - 256;                 // 0..23
        float v = nred[ci >> 2][ci & 3][0] + nred[ci >> 2][ci & 3][1] +
                  nred[ci >> 2][ci & 3][2] + nred[ci >> 2][ci & 3][3] + bcont[ci];
        pcont[(size_t)b * N_CONT + ci] = v;
    }
}

extern "C" void kernel_launch(void* const* d_in, const int* in_sizes, int n_in,
                              void* d_out, int out_size, void* d_ws, size_t ws_size,
                              hipStream_t stream) {
    const float* z     = (const float*)d_in[0];
    // d_in[1] = edge (unused by reference computation)
    const float* Wp    = (const float*)d_in[2];
    const float* bp    = (const float*)d_in[3];
    const float* lnw   = (const float*)d_in[4];
    const float* lnb   = (const float*)d_in[5];
    const float* Wcat  = (const float*)d_in[6];
    const float* bcat  = (const float*)d_in[7];
    const float* Wcont = (const float*)d_in[8];
    const float* bcont = (const float*)d_in[9];

    float* out    = (float*)d_out;
    float* pcat   = out;                                   // [4096, 8, 16]
    float* pcont  = out + (size_t)B_SZ * N_CAT * CAT_D;    // [4096, 24, 1]
    float* latent = pcont + (size_t)B_SZ * N_CONT;         // [4096, 32, 1024]

    u16* zb     = (u16*)d_ws;                              // 4096*1024 bf16 (8 MB)
    u16* Wt     = zb + (size_t)B_SZ * F_DIM;               // 32768*1024 bf16 (64 MB)
    float* murs = (float*)(Wt + (size_t)NTOT * F_DIM);     // 2*4096 f32
    float* psum   = murs + 2 * B_SZ;                       // [4096][256] f32 (4 MB)
    float* psumsq = psum + (size_t)B_SZ * NSTRIP;          // [4096][256] f32 (4 MB)

    zconv<<<dim3(B_SZ * F_DIM / 1024), 256, 0, stream>>>(z, zb);
    transpose_w<<<dim3(16, 16, 32), 256, 0, stream>>>(Wp, Wt);
    gemm_bt<<<dim3(NSTRIP * (B_SZ / 128)), 256, 0, stream>>>(zb, Wt, bp, latent, psum, psumsq);
    ln_finalize<<<dim3(B_SZ), 256, 0, stream>>>(psum, psumsq, murs);
    headsF<<<dim3(B_SZ), 1024, 0, stream>>>(latent, murs, lnw, lnb, Wcat, bcat,
                                            Wcont, bcont, pcat, pcont);
}

// Round 4
// 1005.819 us; speedup vs baseline: 1.1936x; 1.0268x over previous
//
#include <hip/hip_runtime.h>

typedef unsigned short u16;
typedef __bf16 bf16x8 __attribute__((ext_vector_type(8)));
typedef float f32x4 __attribute__((ext_vector_type(4)));

#define B_SZ   4096
#define H_NUM  32
#define F_DIM  1024
#define NTOT   (H_NUM * F_DIM)   // 32768
#define N_CAT  8
#define CAT_D  16
#define N_CONT 24
#define LN_EPS 1e-5f
#define NSTRIP (NTOT / 128)      // 256 n-strips in the GEMM

__device__ __forceinline__ u16 f2bf(float f) {
    unsigned int u = __builtin_bit_cast(unsigned int, f);
    unsigned int r = (u + 0x7FFFu + ((u >> 16) & 1u)) >> 16;
    return (u16)r;
}

__device__ __forceinline__ void gl2lds16(const void* g, void* l) {
    __builtin_amdgcn_global_load_lds(
        (const __attribute__((address_space(1))) void*)g,
        (__attribute__((address_space(3))) void*)l,
        16, 0, 0);
}

__device__ __forceinline__ float wave_sum(float v) {
#pragma unroll
    for (int o = 32; o; o >>= 1) v += __shfl_xor(v, o);
    return v;
}

// ---------------- z f32 -> bf16 ----------------
__global__ __launch_bounds__(256) void zconv(const float* __restrict__ z,
                                             u16* __restrict__ zb) {
    int i = blockIdx.x * 256 + threadIdx.x;      // one float4 per thread
    float4 v = ((const float4*)z)[i];
    ushort4 o;
    o.x = f2bf(v.x); o.y = f2bf(v.y); o.z = f2bf(v.z); o.w = f2bf(v.w);
    ((ushort4*)zb)[i] = o;
}

// ---------------- W_proj [h][f][d] f32 -> Wt [h][d][f] bf16 ----------------
__global__ __launch_bounds__(256) void transpose_w(const float* __restrict__ W,
                                                   u16* __restrict__ Wt) {
    __shared__ u16 tile[64][72];
    const int h = blockIdx.z;
    const int f0 = blockIdx.x * 64;
    const int d0 = blockIdx.y * 64;
    const float* Wh = W + (size_t)h * F_DIM * F_DIM;
    u16* Wth = Wt + (size_t)h * F_DIM * F_DIM;
    const int t = threadIdx.x;

#pragma unroll
    for (int i = 0; i < 4; ++i) {
        int idx = i * 256 + t;        // 0..1023
        int fr = idx >> 4;            // 0..63
        int c4 = idx & 15;            // 0..15
        float4 v = *(const float4*)(Wh + (size_t)(f0 + fr) * F_DIM + d0 + c4 * 4);
        tile[fr][c4 * 4 + 0] = f2bf(v.x);
        tile[fr][c4 * 4 + 1] = f2bf(v.y);
        tile[fr][c4 * 4 + 2] = f2bf(v.z);
        tile[fr][c4 * 4 + 3] = f2bf(v.w);
    }
    __syncthreads();
#pragma unroll
    for (int i = 0; i < 2; ++i) {
        int idx = i * 256 + t;        // 0..511
        int dr = idx >> 3;            // 0..63
        int c8 = idx & 7;             // 0..7
        __attribute__((aligned(16))) u16 tmp[8];
#pragma unroll
        for (int j = 0; j < 8; ++j) tmp[j] = tile[c8 * 8 + j][dr];
        *(uint4*)(Wth + (size_t)(d0 + dr) * F_DIM + f0 + c8 * 8) = *(const uint4*)tmp;
    }
}

// ---------------- GEMM + per-block LN partial sums ----------------
__global__ __launch_bounds__(256) void gemm_bt(const u16* __restrict__ A,
                                               const u16* __restrict__ Bt,
                                               const float* __restrict__ bproj,
                                               float* __restrict__ C,
                                               float* __restrict__ psum,
                                               float* __restrict__ psumsq) {
    __shared__ u16 sA[128 * 64];
    __shared__ u16 sB[128 * 64];
    __shared__ float sred[2][128];
    __shared__ float s2red[2][128];
    const int t = threadIdx.x;
    const int wid = t >> 6;
    const int lane = t & 63;
    const int l16 = lane & 15;
    const int lk = lane >> 4;
    const int wr = wid >> 1;
    const int wc = wid & 1;

    // XCD-aware bijective swizzle (nwg = 8192, 8192 % 8 == 0)
    const int nwg = NSTRIP * (B_SZ / 128);           // 8192
    const int q = nwg >> 3;
    const int wg = blockIdx.x;
    const int sw = (wg & 7) * q + (wg >> 3);
    const int m0 = (sw / NSTRIP) * 128;
    const int n0 = (sw % NSTRIP) * 128;

    f32x4 acc[4][4];
    const f32x4 zero = {0.f, 0.f, 0.f, 0.f};
#pragma unroll
    for (int m = 0; m < 4; ++m)
#pragma unroll
        for (int n = 0; n < 4; ++n) acc[m][n] = zero;

    for (int k0 = 0; k0 < 1024; k0 += 64) {
#pragma unroll
        for (int q2 = 0; q2 < 4; ++q2) {
            int ci = q2 * 256 + t;
            int r = ci >> 3, c8 = ci & 7;
            gl2lds16(A + ((size_t)(m0 + r) << 10) + k0 + c8 * 8,
                     sA + (size_t)(q2 * 256 + (wid << 6)) * 8);
        }
#pragma unroll
        for (int q2 = 0; q2 < 4; ++q2) {
            int ci = q2 * 256 + t;
            int r = ci >> 3, c8 = ci & 7;
            gl2lds16(Bt + ((size_t)(n0 + r) << 10) + k0 + c8 * 8,
                     sB + (size_t)(q2 * 256 + (wid << 6)) * 8);
        }
        __syncthreads();
#pragma unroll
        for (int kk = 0; kk < 64; kk += 32) {
            bf16x8 a[4], bf[4];
#pragma unroll
            for (int m = 0; m < 4; ++m)
                a[m] = *(const bf16x8*)(sA + (wr * 64 + m * 16 + l16) * 64 + kk + lk * 8);
#pragma unroll
            for (int n = 0; n < 4; ++n)
                bf[n] = *(const bf16x8*)(sB + (wc * 64 + n * 16 + l16) * 64 + kk + lk * 8);
#pragma unroll
            for (int m = 0; m < 4; ++m)
#pragma unroll
                for (int n = 0; n < 4; ++n)
                    acc[m][n] = __builtin_amdgcn_mfma_f32_16x16x32_bf16(a[m], bf[n], acc[m][n], 0, 0, 0);
        }
        __syncthreads();
    }

    // epilogue: C-write + per-row (sum, sumsq) over this block's 128 cols
    float sm[4][4], s2m[4][4];
#pragma unroll
    for (int m = 0; m < 4; ++m)
#pragma unroll
        for (int j = 0; j < 4; ++j) { sm[m][j] = 0.f; s2m[m][j] = 0.f; }

#pragma unroll
    for (int n = 0; n < 4; ++n) {
        int col = n0 + wc * 64 + n * 16 + l16;
        float bias = bproj[col];
#pragma unroll
        for (int m = 0; m < 4; ++m) {
            int rbase = m0 + wr * 64 + m * 16 + lk * 4;
#pragma unroll
            for (int j = 0; j < 4; ++j) {
                float v = acc[m][n][j] + bias;
                C[(size_t)(rbase + j) * NTOT + col] = v;
                sm[m][j] += v;
                s2m[m][j] += v * v;
            }
        }
    }
    // reduce over the 16 l16 lanes (same rows, different cols)
#pragma unroll
    for (int o = 1; o < 16; o <<= 1) {
#pragma unroll
        for (int m = 0; m < 4; ++m)
#pragma unroll
            for (int j = 0; j < 4; ++j) {
                sm[m][j] += __shfl_xor(sm[m][j], o);
                s2m[m][j] += __shfl_xor(s2m[m][j], o);
            }
    }
    if (l16 == 0) {
#pragma unroll
        for (int m = 0; m < 4; ++m)
#pragma unroll
            for (int j = 0; j < 4; ++j) {
                int r = wr * 64 + m * 16 + lk * 4 + j;
                sred[wc][r] = sm[m][j];
                s2red[wc][r] = s2m[m][j];
            }
    }
    __syncthreads();
    if (t < 128) {
        int strip = n0 >> 7;
        psum[(size_t)(m0 + t) * NSTRIP + strip] = sred[0][t] + sred[1][t];
        psumsq[(size_t)(m0 + t) * NSTRIP + strip] = s2red[0][t] + s2red[1][t];
    }
}

// ---------------- finalize LN stats from partials ----------------
__global__ __launch_bounds__(256) void ln_finalize(const float* __restrict__ psum,
                                                   const float* __restrict__ psumsq,
                                                   float* __restrict__ murs) {
    const int b = blockIdx.x;
    const int t = threadIdx.x;
    float s = psum[(size_t)b * NSTRIP + t];
    float s2 = psumsq[(size_t)b * NSTRIP + t];
    s = wave_sum(s);
    s2 = wave_sum(s2);
    __shared__ float red[8];
    int wid = t >> 6, lane = t & 63;
    if (lane == 0) { red[wid] = s; red[4 + wid] = s2; }
    __syncthreads();
    if (t == 0) {
        float S = red[0] + red[1] + red[2] + red[3];
        float S2 = red[4] + red[5] + red[6] + red[7];
        float m = S / (float)NTOT;
        float var = S2 / (float)NTOT - m * m;
        murs[b] = m;
        murs[B_SZ + b] = rsqrtf(var + LN_EPS);
    }
}

// ---------------- normalize + relu + heads: one 256-thread block per b ----------------
// Iteration k covers head k exactly: i = 256k + t (coalesced float4s).
__global__ __launch_bounds__(256, 8) void headsG(float* __restrict__ lat_base,
                                                 const float* __restrict__ murs,
                                                 const float* __restrict__ lnw,
                                                 const float* __restrict__ lnb,
                                                 const float* __restrict__ Wcat,
                                                 const float* __restrict__ bcat,
                                                 const float* __restrict__ Wcont,
                                                 const float* __restrict__ bcont,
                                                 float* __restrict__ pcat,
                                                 float* __restrict__ pcont) {
    const int b = blockIdx.x;
    const int t = threadIdx.x;
    const int lane = t & 63;
    const int w4 = t >> 6;                    // wave 0..3
    const float mu = murs[b];
    const float rs = murs[B_SZ + b];
    float4* lat4 = (float4*)(lat_base + (size_t)b * NTOT);
    const float4* lnw4 = (const float4*)lnw;
    const float4* lnb4 = (const float4*)lnb;
    const float4* wcont4 = (const float4*)Wcont;

    __shared__ float4 sy4[256];               // one head row of y
    __shared__ float cred[4][N_CAT][CAT_D];   // per-wave cat partials
    __shared__ float nred[N_CONT][4];         // per-wave cont partials

    // ---- categorical heads (k = h = 0..7): stage y in LDS, short-reduce GEMV ----
    for (int k = 0; k < N_CAT; ++k) {
        const int i = (k << 8) + t;
        float4 x = lat4[i];
        float4 w = lnw4[i];
        float4 bv = lnb4[i];
        float4 yo;
        yo.x = fmaxf(0.f, (x.x - mu) * rs * w.x + bv.x);
        yo.y = fmaxf(0.f, (x.y - mu) * rs * w.y + bv.y);
        yo.z = fmaxf(0.f, (x.z - mu) * rs * w.z + bv.z);
        yo.w = fmaxf(0.f, (x.w - mu) * rs * w.w + bv.w);
        lat4[i] = yo;
        sy4[t] = yo;
        __syncthreads();

        const int c = t & 15;                 // category column
        const int g = t >> 4;                 // f-group: f = g*64 .. g*64+63
        const float* Wc = Wcat + (size_t)k * F_DIM * CAT_D + c;
        float acc = 0.f;
#pragma unroll
        for (int j = 0; j < 16; ++j) {
            float4 yv = sy4[g * 16 + j];
            int fb = (g * 64 + j * 4) * CAT_D;
            acc += yv.x * Wc[fb] + yv.y * Wc[fb + CAT_D] +
                   yv.z * Wc[fb + 2 * CAT_D] + yv.w * Wc[fb + 3 * CAT_D];
        }
        acc += __shfl_xor(acc, 16);
        acc += __shfl_xor(acc, 32);
        if (lane < 16) cred[w4][k][lane] = acc;
        __syncthreads();
    }

    // ---- continuous heads (k = 8..31): barrier-free streaming ----
#pragma unroll 2
    for (int k = N_CAT; k < H_NUM; ++k) {
        const int i = (k << 8) + t;
        float4 x = lat4[i];
        float4 w = lnw4[i];
        float4 bv = lnb4[i];
        float4 yo;
        yo.x = fmaxf(0.f, (x.x - mu) * rs * w.x + bv.x);
        yo.y = fmaxf(0.f, (x.y - mu) * rs * w.y + bv.y);
        yo.z = fmaxf(0.f, (x.z - mu) * rs * w.z + bv.z);
        yo.w = fmaxf(0.f, (x.w - mu) * rs * w.w + bv.w);
        lat4[i] = yo;
        float4 wv = wcont4[((k - N_CAT) << 8) + t];
        float part = yo.x * wv.x + yo.y * wv.y + yo.z * wv.z + yo.w * wv.w;
        part = wave_sum(part);
        if (lane == 0) nred[k - N_CAT][w4] = part;
    }
    __syncthreads();

    // ---- finalize ----
    if (t < 128) {                            // cat softmax: h = t>>4, c = t&15
        const int h = t >> 4, c = t & 15;
        float lg = cred[0][h][c] + cred[1][h][c] + cred[2][h][c] + cred[3][h][c] +
                   bcat[h * CAT_D + c];
        float mx = lg;
#pragma unroll
        for (int o = 8; o; o >>= 1) mx = fmaxf(mx, __shfl_xor(mx, o, 16));
        float e = __expf(lg - mx);
        float sm2 = e;
#pragma unroll
        for (int o = 8; o; o >>= 1) sm2 += __shfl_xor(sm2, o, 16);
        pcat[(size_t)b * (N_CAT * CAT_D) + t] = e / sm2;
    } else if (t >= 128 && t < 128 + N_CONT) {
        const int ci = t - 128;
        pcont[(size_t)b * N_CONT + ci] =
            nred[ci][0] + nred[ci][1] + nred[ci][2] + nred[ci][3] + bcont[ci];
    }
}

extern "C" void kernel_launch(void* const* d_in, const int* in_sizes, int n_in,
                              void* d_out, int out_size, void* d_ws, size_t ws_size,
                              hipStream_t stream) {
    const float* z     = (const float*)d_in[0];
    // d_in[1] = edge (unused by reference computation)
    const float* Wp    = (const float*)d_in[2];
    const float* bp    = (const float*)d_in[3];
    const float* lnw   = (const float*)d_in[4];
    const float* lnb   = (const float*)d_in[5];
    const float* Wcat  = (const float*)d_in[6];
    const float* bcat  = (const float*)d_in[7];
    const float* Wcont = (const float*)d_in[8];
    const float* bcont = (const float*)d_in[9];

    float* out    = (float*)d_out;
    float* pcat   = out;                                   // [4096, 8, 16]
    float* pcont  = out + (size_t)B_SZ * N_CAT * CAT_D;    // [4096, 24, 1]
    float* latent = pcont + (size_t)B_SZ * N_CONT;         // [4096, 32, 1024]

    u16* zb     = (u16*)d_ws;                              // 4096*1024 bf16 (8 MB)
    u16* Wt     = zb + (size_t)B_SZ * F_DIM;               // 32768*1024 bf16 (64 MB)
    float* murs = (float*)(Wt + (size_t)NTOT * F_DIM);     // 2*4096 f32
    float* psum   = murs + 2 * B_SZ;                       // [4096][256] f32 (4 MB)
    float* psumsq = psum + (size_t)B_SZ * NSTRIP;          // [4096][256] f32 (4 MB)

    zconv<<<dim3(B_SZ * F_DIM / 1024), 256, 0, stream>>>(z, zb);
    transpose_w<<<dim3(16, 16, 32), 256, 0, stream>>>(Wp, Wt);
    gemm_bt<<<dim3(NSTRIP * (B_SZ / 128)), 256, 0, stream>>>(zb, Wt, bp, latent, psum, psumsq);
    ln_finalize<<<dim3(B_SZ), 256, 0, stream>>>(psum, psumsq, murs);
    headsG<<<dim3(B_SZ), 256, 0, stream>>>(latent, murs, lnw, lnb, Wcat, bcat,
                                           Wcont, bcont, pcat, pcont);
}